// Round 2
// baseline (58.163 us; speedup 1.0000x reference)
//
#include <hip/hip_runtime.h>

#define S_LEN 4096
#define Dh 64
#define BQ 64
#define BK 64
#define THREADS 256
#define NXCD 8

typedef __attribute__((ext_vector_type(8))) short bf16x8;
typedef __attribute__((ext_vector_type(4))) float f32x4;
typedef __attribute__((ext_vector_type(4))) short bf16x4;

__device__ __forceinline__ short f2bf(float f) {
    union { float f; unsigned u; } c; c.f = f;
    unsigned u = c.u + 0x7FFFu + ((c.u >> 16) & 1u);
    return (short)(u >> 16);
}

__global__ __launch_bounds__(THREADS, 4) void swin_attn(
    const float* __restrict__ q, const float* __restrict__ k,
    const float* __restrict__ qr, const float* __restrict__ kr,
    const float* __restrict__ v, const int* __restrict__ hor,
    float* __restrict__ out)
{
    const int W = hor[0];

    // XCD-aware bijective swizzle: gridDim.x = 1024 (divisible by 8).
    const int nwg = gridDim.x;
    const int cpx = nwg >> 3;                       // 128 blocks per XCD chunk
    const int wg = (blockIdx.x & (NXCD - 1)) * cpx + (blockIdx.x >> 3);
    const int bh = wg >> 6;                         // 0..15
    const int q0 = (wg & 63) * BQ;                  // 0..4032
    const size_t base = (size_t)bh * S_LEN * Dh;

    const int tid = threadIdx.x;
    const int lane = tid & 63;
    const int wv = tid >> 6;        // 0..3, each wave owns 16 q rows
    const int g = lane >> 4;        // 0..3
    const int l16 = lane & 15;      // 0..15

    // LDS: K(concat) [64 keys][128 feats] bf16 swizzled (16KB);
    //      Vt [64 e][64 keys] bf16 swizzled (8KB);
    //      S per-wave [16 q][64 keys] bf16 swizzled (4x2KB). Total 32KB.
    __shared__ __align__(16) char sK[BK * 256];
    __shared__ __align__(16) char sV[64 * 128];
    __shared__ __align__(16) char sS[4][16 * 128];

    // ---- Q fragments (A-layout: row=l16, k=g*8+j), feat concat q||qr
    bf16x8 qf[4];
    {
        int qg = q0 + wv * 16 + l16;
        const float* qrow  = q  + base + (size_t)qg * Dh;
        const float* qrrow = qr + base + (size_t)qg * Dh;
        #pragma unroll
        for (int fb = 0; fb < 4; ++fb) {
            int feat = fb * 32 + g * 8;
            const float* src = (feat < 64) ? (qrow + feat) : (qrrow + (feat - 64));
            f32x4 a = *(const f32x4*)src;
            f32x4 b = *(const f32x4*)(src + 4);
            bf16x8 fr;
            #pragma unroll
            for (int j = 0; j < 4; ++j) { fr[j] = f2bf(a[j]); fr[4 + j] = f2bf(b[j]); }
            qf[fb] = fr;
        }
    }

    f32x4 nacc[4];
    f32x4 dacc = (f32x4){0.f, 0.f, 0.f, 0.f};
    #pragma unroll
    for (int eb = 0; eb < 4; ++eb) nacc[eb] = (f32x4){0.f, 0.f, 0.f, 0.f};
    bf16x8 ones;
    #pragma unroll
    for (int j = 0; j < 8; ++j) ones[j] = (short)0x3F80;  // bf16 1.0

    const int lo_key = q0 - (W - 1);
    const int kt_lo = (lo_key <= 0) ? 0 : (lo_key >> 6);
    const int kt_hi = q0 >> 6;

    for (int kt = kt_lo; kt <= kt_hi; ++kt) {
        const int k0 = kt << 6;
        __syncthreads();  // previous tile's readers done before overwrite

        // ---- stage K||Kr tile: [64][128] bf16, b128 writes, XOR swizzle
        #pragma unroll
        for (int i = 0; i < 4; ++i) {
            int c = tid + THREADS * i;      // 1024 chunks of 8 feats
            int row = c >> 4;
            int f0 = (c & 15) * 8;
            const float* src = (f0 < 64) ? (k  + base + (size_t)(k0 + row) * Dh + f0)
                                         : (kr + base + (size_t)(k0 + row) * Dh + (f0 - 64));
            f32x4 a = *(const f32x4*)src;
            f32x4 b = *(const f32x4*)(src + 4);
            bf16x8 w8;
            #pragma unroll
            for (int j = 0; j < 4; ++j) { w8[j] = f2bf(a[j]); w8[4 + j] = f2bf(b[j]); }
            int off = row * 256 + ((f0 * 2) ^ ((row & 7) << 4));
            *(bf16x8*)(sK + off) = w8;
        }
        // ---- stage V transposed, PACKED: thread owns (e, key4-group) -> ds_write_b64
        #pragma unroll
        for (int i = 0; i < 4; ++i) {
            int c = tid + THREADS * i;      // 1024 chunks: e(64) x key4(16)
            int e = c & 63;
            int k4 = c >> 6;                // 0..15
            const float* src = v + base + (size_t)(k0 + k4 * 4) * Dh + e;
            float a0 = src[0];
            float a1 = src[Dh];
            float a2 = src[2 * Dh];
            float a3 = src[3 * Dh];
            bf16x4 w4;
            w4[0] = f2bf(a0); w4[1] = f2bf(a1); w4[2] = f2bf(a2); w4[3] = f2bf(a3);
            int off = e * 128 + ((k4 * 8) ^ ((e & 7) << 4));
            *(bf16x4*)(sV + off) = w4;
        }
        __syncthreads();

        const bool dense = (k0 + BK - 1 <= q0) && (k0 >= q0 + BQ - 1 - (W - 1));

        // ---- QK^T (K=128) -> mask -> S to wave-private LDS (bf16, swizzled)
        #pragma unroll
        for (int kb = 0; kb < 4; ++kb) {
            bf16x8 kf[4];
            const int key = kb * 16 + l16;
            const int rowoff = key * 256;
            const int sw = (key & 7) << 4;
            #pragma unroll
            for (int fb = 0; fb < 4; ++fb)
                kf[fb] = *(const bf16x8*)(sK + rowoff + ((fb * 64 + g * 16) ^ sw));
            f32x4 s = {0.f, 0.f, 0.f, 0.f};
            #pragma unroll
            for (int fb = 0; fb < 4; ++fb)
                s = __builtin_amdgcn_mfma_f32_16x16x32_bf16(qf[fb], kf[fb], s, 0, 0, 0);
            const int qrow0 = g * 4;                       // in-wave q row
            const int qg0 = q0 + wv * 16 + qrow0;          // global q
            const int mg = k0 + kb * 16 + l16;             // global key
            if (!dense) {
                #pragma unroll
                for (int r = 0; r < 4; ++r) {
                    unsigned d = (unsigned)(qg0 + r - mg);
                    if (d >= (unsigned)W) s[r] = 0.f;
                }
            }
            #pragma unroll
            for (int r = 0; r < 4; ++r) {
                int row = qrow0 + r;
                int off = row * 128 + (((kb * 16 + l16) * 2) ^ ((row & 7) << 4));
                *(short*)(sS[wv] + off) = f2bf(s[r]);
            }
        }

        // ---- PV (K-dim = 64 keys) + denominator via ones-B MFMA
        #pragma unroll
        for (int kb2 = 0; kb2 < 2; ++kb2) {
            int arow = l16;
            int aoff = arow * 128 + ((kb2 * 64 + g * 16) ^ ((arow & 7) << 4));
            bf16x8 af = *(const bf16x8*)(sS[wv] + aoff);
            dacc = __builtin_amdgcn_mfma_f32_16x16x32_bf16(af, ones, dacc, 0, 0, 0);
            #pragma unroll
            for (int eb = 0; eb < 4; ++eb) {
                int e = eb * 16 + l16;
                int off = e * 128 + ((kb2 * 64 + g * 16) ^ ((e & 7) << 4));
                bf16x8 bfr = *(const bf16x8*)(sV + off);
                nacc[eb] = __builtin_amdgcn_mfma_f32_16x16x32_bf16(af, bfr, nacc[eb], 0, 0, 0);
            }
        }
    }

    // ---- epilogue: out = N / (D + eps); D row-aligned with N (ones-B trick)
    f32x4 rc;
    #pragma unroll
    for (int r = 0; r < 4; ++r) rc[r] = 1.0f / (dacc[r] + 1e-12f);
    const int qg0 = q0 + wv * 16 + g * 4;
    #pragma unroll
    for (int eb = 0; eb < 4; ++eb) {
        #pragma unroll
        for (int r = 0; r < 4; ++r) {
            out[base + (size_t)(qg0 + r) * Dh + eb * 16 + l16] = nacc[eb][r] * rc[r];
        }
    }
}

extern "C" void kernel_launch(void* const* d_in, const int* in_sizes, int n_in,
                              void* d_out, int out_size, void* d_ws, size_t ws_size,
                              hipStream_t stream) {
    const float* q  = (const float*)d_in[0];
    const float* k  = (const float*)d_in[1];
    const float* qr = (const float*)d_in[2];
    const float* kr = (const float*)d_in[3];
    const float* v  = (const float*)d_in[4];
    const int* hor  = (const int*)d_in[5];
    float* out = (float*)d_out;

    const int BH = in_sizes[0] / (S_LEN * Dh);   // B*H = 16
    dim3 grid((S_LEN / BQ) * BH);                // 1024 blocks
    hipLaunchKernelGGL(swin_attn, grid, dim3(THREADS), 0, stream,
                       q, k, qr, kr, v, hor, out);
}

// Round 3
// 52.657 us; speedup vs baseline: 1.1046x; 1.1046x over previous
//
#include <hip/hip_runtime.h>

#define S_LEN 4096
#define Dh 64
#define THREADS 256
#define KC_TILE 16384
#define VT_TILE 8192
#define VT_BASE 16777216ull
#define WS_NEED 25165824ull

typedef __attribute__((ext_vector_type(8))) short bf16x8;
typedef __attribute__((ext_vector_type(4))) float f32x4;
typedef __attribute__((ext_vector_type(4))) short bf16x4;

__device__ __forceinline__ short f2bf(float f) {
    union { float f; unsigned u; } c; c.f = f;
    unsigned u = c.u + 0x7FFFu + ((c.u >> 16) & 1u);
    return (short)(u >> 16);
}

__device__ __forceinline__ void gload16(const void* g, void* l) {
    __builtin_amdgcn_global_load_lds(
        (const __attribute__((address_space(1))) unsigned int*)g,
        (__attribute__((address_space(3))) unsigned int*)l, 16, 0, 0);
}

// ---------------- prepack: fp32 k||kr, v  ->  bf16 swizzled LDS tile images in ws
// Kc image per (bh, tile of 64 keys): row r, feat f (0..127 = k||kr):
//   byte off = r*256 + ((f*2) ^ ((r&7)<<4)), 16KB per tile, base 0.
// Vt image per (bh, tile): e (0..63), key kk (0..63):
//   byte off = e*128 + ((kk*2) ^ ((e&7)<<4)), 8KB per tile, base VT_BASE.
__global__ __launch_bounds__(THREADS) void prepack(
    const float* __restrict__ k, const float* __restrict__ kr,
    const float* __restrict__ v, char* __restrict__ ws)
{
    const int t = blockIdx.x * THREADS + threadIdx.x;   // 0 .. 2^20-1
    // ---- K chunk: 16B = 8 feats of one row
    {
        const int bh = t >> 16;
        const int r1 = t & 65535;
        const int tile = r1 >> 10;
        const int r2 = r1 & 1023;
        const int row = r2 >> 4;
        const int f0 = (r2 & 15) * 8;
        const size_t rbase = ((size_t)bh * S_LEN + tile * 64 + row) * Dh;
        const float* src = (f0 < 64) ? (k + rbase + f0) : (kr + rbase + (f0 - 64));
        f32x4 a = *(const f32x4*)src;
        f32x4 b = *(const f32x4*)(src + 4);
        bf16x8 w;
        #pragma unroll
        for (int j = 0; j < 4; ++j) { w[j] = f2bf(a[j]); w[4 + j] = f2bf(b[j]); }
        const int off = row * 256 + ((f0 * 2) ^ ((row & 7) << 4));
        *(bf16x8*)(ws + (size_t)(bh * 64 + tile) * KC_TILE + off) = w;
    }
    // ---- V chunk: 8B = 4 keys of one e (transposed)
    {
        const int bh = t >> 16;
        const int r1 = t & 65535;
        const int tile = r1 >> 10;
        const int r2 = r1 & 1023;
        const int e = r2 & 63;
        const int k4 = r2 >> 6;       // 0..15
        const float* src = v + ((size_t)bh * S_LEN + tile * 64 + k4 * 4) * Dh + e;
        bf16x4 w;
        w[0] = f2bf(src[0]);
        w[1] = f2bf(src[Dh]);
        w[2] = f2bf(src[2 * Dh]);
        w[3] = f2bf(src[3 * Dh]);
        const int off = e * 128 + ((k4 * 8) ^ ((e & 7) << 4));
        *(bf16x4*)(ws + VT_BASE + (size_t)(bh * 64 + tile) * VT_TILE + off) = w;
    }
}

// ---------------- main: BQ=128, 4 waves, double-buffered global_load_lds pipeline
__global__ __launch_bounds__(THREADS, 2) void swin_attn2(
    const float* __restrict__ q, const float* __restrict__ qr,
    const char* __restrict__ ws, const int* __restrict__ hor,
    float* __restrict__ out)
{
    const int W = hor[0];
    const int bid = blockIdx.x;                     // 512 blocks, 512%8==0
    const int wg = (bid & 7) * 64 + (bid >> 3);     // XCD-aware bijective swizzle
    const int bh = wg >> 5;                         // 0..15
    const int q0 = (wg & 31) * 128;                 // 0..3968
    const size_t base = (size_t)bh * S_LEN * Dh;

    const int tid = threadIdx.x;
    const int lane = tid & 63;
    const int wv = tid >> 6;        // wave owns 32 q rows
    const int g = lane >> 4;
    const int l16 = lane & 15;

    __shared__ __align__(16) char sK[2][KC_TILE];   // 32KB
    __shared__ __align__(16) char sV[2][VT_TILE];   // 16KB
    __shared__ __align__(16) char sS[4][4096];      // 16KB  (wave-private S)

    // ---- Q fragments (row=l16, k=g*8+j), feat concat q||qr
    bf16x8 qf[2][4];
    #pragma unroll
    for (int rb = 0; rb < 2; ++rb) {
        int qg = q0 + wv * 32 + rb * 16 + l16;
        const float* qrow  = q  + base + (size_t)qg * Dh;
        const float* qrrow = qr + base + (size_t)qg * Dh;
        #pragma unroll
        for (int fb = 0; fb < 4; ++fb) {
            int feat = fb * 32 + g * 8;
            const float* src = (feat < 64) ? (qrow + feat) : (qrrow + (feat - 64));
            f32x4 a = *(const f32x4*)src;
            f32x4 b = *(const f32x4*)(src + 4);
            bf16x8 fr;
            #pragma unroll
            for (int j = 0; j < 4; ++j) { fr[j] = f2bf(a[j]); fr[4 + j] = f2bf(b[j]); }
            qf[rb][fb] = fr;
        }
    }

    f32x4 nacc[2][4];
    f32x4 dacc[2];
    #pragma unroll
    for (int rb = 0; rb < 2; ++rb) {
        dacc[rb] = (f32x4){0.f, 0.f, 0.f, 0.f};
        #pragma unroll
        for (int eb = 0; eb < 4; ++eb) nacc[rb][eb] = (f32x4){0.f, 0.f, 0.f, 0.f};
    }
    bf16x8 ones;
    #pragma unroll
    for (int j = 0; j < 8; ++j) ones[j] = (short)0x3F80;

    const int lo_key = q0 - (W - 1);
    const int kt_lo = (lo_key <= 0) ? 0 : (lo_key >> 6);
    const int kt_hi = (q0 + 127) >> 6;

    const char* KcB = ws + (size_t)(bh << 6) * KC_TILE;
    const char* VtB = ws + VT_BASE + (size_t)(bh << 6) * VT_TILE;

    // Drain Q/hor loads so vmcnt counts ONLY staging loads from here on.
    asm volatile("s_waitcnt vmcnt(0)" ::: "memory");
    __builtin_amdgcn_sched_barrier(0);

#define STAGE(B, KT)                                                              \
    do {                                                                          \
        const char* kg_ = KcB + (size_t)(KT) * KC_TILE + wv * 4096 + lane * 16;   \
        const char* vg_ = VtB + (size_t)(KT) * VT_TILE + wv * 2048 + lane * 16;   \
        _Pragma("unroll")                                                         \
        for (int i_ = 0; i_ < 4; ++i_)                                            \
            gload16(kg_ + i_ * 1024, &sK[B][wv * 4096 + i_ * 1024]);              \
        _Pragma("unroll")                                                         \
        for (int i_ = 0; i_ < 2; ++i_)                                            \
            gload16(vg_ + i_ * 1024, &sV[B][wv * 2048 + i_ * 1024]);              \
    } while (0)

    STAGE(0, kt_lo);    // prologue: 6 loads/wave in flight

    int buf = 0;
    for (int kt = kt_lo; kt <= kt_hi; ++kt) {
        const int k0 = kt << 6;
        const bool more = (kt < kt_hi);
        if (more) {
            STAGE(buf ^ 1, kt + 1);                       // +6 -> 12 outstanding
            asm volatile("s_waitcnt vmcnt(6)" ::: "memory");  // cur tile landed
        } else {
            asm volatile("s_waitcnt vmcnt(0)" ::: "memory");
        }
        __builtin_amdgcn_sched_barrier(0);
        __builtin_amdgcn_s_barrier();                     // all waves' cur loads visible
        asm volatile("" ::: "memory");

        const char* Kb = sK[buf];
        const char* Vb = sV[buf];
        const bool dense = (k0 + 63 <= q0) && (k0 >= q0 + 127 - (W - 1));

        // ---- QK^T (K=128) -> mask -> S to wave-private LDS (bf16, swizzled)
        #pragma unroll
        for (int kb = 0; kb < 4; ++kb) {
            bf16x8 kf[4];
            const int key = kb * 16 + l16;
            const int rowoff = key * 256;
            const int sw = (key & 7) << 4;
            #pragma unroll
            for (int fb = 0; fb < 4; ++fb)
                kf[fb] = *(const bf16x8*)(Kb + rowoff + ((fb * 64 + g * 16) ^ sw));
            #pragma unroll
            for (int rb = 0; rb < 2; ++rb) {
                f32x4 s = {0.f, 0.f, 0.f, 0.f};
                #pragma unroll
                for (int fb = 0; fb < 4; ++fb)
                    s = __builtin_amdgcn_mfma_f32_16x16x32_bf16(qf[rb][fb], kf[fb], s, 0, 0, 0);
                const int qrow0 = rb * 16 + g * 4;
                const int qg0 = q0 + wv * 32 + qrow0;
                const int mg = k0 + kb * 16 + l16;
                if (!dense) {
                    #pragma unroll
                    for (int r = 0; r < 4; ++r) {
                        unsigned d = (unsigned)(qg0 + r - mg);
                        if (d >= (unsigned)W) s[r] = 0.f;
                    }
                }
                #pragma unroll
                for (int r = 0; r < 4; ++r) {
                    int row = qrow0 + r;
                    int off = row * 128 + (((kb * 16 + l16) * 2) ^ ((row & 7) << 4));
                    *(short*)(sS[wv] + off) = f2bf(s[r]);
                }
            }
        }

        // ---- PV (64 keys) + denominator via ones-B MFMA
        #pragma unroll
        for (int kb2 = 0; kb2 < 2; ++kb2) {
            bf16x8 af[2];
            #pragma unroll
            for (int rb = 0; rb < 2; ++rb) {
                int row = rb * 16 + l16;
                int off = row * 128 + ((kb2 * 64 + g * 16) ^ ((row & 7) << 4));
                af[rb] = *(const bf16x8*)(sS[wv] + off);
            }
            #pragma unroll
            for (int rb = 0; rb < 2; ++rb)
                dacc[rb] = __builtin_amdgcn_mfma_f32_16x16x32_bf16(af[rb], ones, dacc[rb], 0, 0, 0);
            #pragma unroll
            for (int eb = 0; eb < 4; ++eb) {
                int e = eb * 16 + l16;
                int off = e * 128 + ((kb2 * 64 + g * 16) ^ ((e & 7) << 4));
                bf16x8 bfr = *(const bf16x8*)(Vb + off);
                #pragma unroll
                for (int rb = 0; rb < 2; ++rb)
                    nacc[rb][eb] = __builtin_amdgcn_mfma_f32_16x16x32_bf16(af[rb], bfr, nacc[rb][eb], 0, 0, 0);
            }
        }

        asm volatile("" ::: "memory");
        __builtin_amdgcn_s_barrier();   // readers done before next STAGE overwrites
        buf ^= 1;
    }
#undef STAGE

    // ---- epilogue
    #pragma unroll
    for (int rb = 0; rb < 2; ++rb) {
        f32x4 rc;
        #pragma unroll
        for (int r = 0; r < 4; ++r) rc[r] = 1.0f / (dacc[rb][r] + 1e-12f);
        const int qg0 = q0 + wv * 32 + rb * 16 + g * 4;
        #pragma unroll
        for (int eb = 0; eb < 4; ++eb) {
            #pragma unroll
            for (int r = 0; r < 4; ++r) {
                out[base + (size_t)(qg0 + r) * Dh + eb * 16 + l16] = nacc[rb][eb][r] * rc[r];
            }
        }
    }
}

// ---------------- fallback (round-1 proven kernel) if ws too small
__global__ __launch_bounds__(THREADS, 2) void swin_attn_fb(
    const float* __restrict__ q, const float* __restrict__ k,
    const float* __restrict__ qr, const float* __restrict__ kr,
    const float* __restrict__ v, const int* __restrict__ hor,
    float* __restrict__ out)
{
    const int W = hor[0];
    const int q0 = blockIdx.x * 128;
    const int bh = blockIdx.y;
    const size_t base = (size_t)bh * S_LEN * Dh;

    const int tid = threadIdx.x;
    const int lane = tid & 63;
    const int wv = tid >> 6;
    const int g = lane >> 4;
    const int l16 = lane & 15;

    __shared__ __align__(16) char sK[64 * 256];
    __shared__ __align__(16) char sV[64 * 128];
    __shared__ __align__(16) char sS[4][32 * 128];

    bf16x8 qf[2][4];
    #pragma unroll
    for (int rb = 0; rb < 2; ++rb) {
        int qg = q0 + wv * 32 + rb * 16 + l16;
        const float* qrow  = q  + base + (size_t)qg * Dh;
        const float* qrrow = qr + base + (size_t)qg * Dh;
        #pragma unroll
        for (int fb = 0; fb < 4; ++fb) {
            int feat = fb * 32 + g * 8;
            const float* src = (feat < 64) ? (qrow + feat) : (qrrow + (feat - 64));
            f32x4 a = *(const f32x4*)src;
            f32x4 b = *(const f32x4*)(src + 4);
            bf16x8 fr;
            #pragma unroll
            for (int j = 0; j < 4; ++j) { fr[j] = f2bf(a[j]); fr[4 + j] = f2bf(b[j]); }
            qf[rb][fb] = fr;
        }
    }

    f32x4 nacc[2][4];
    f32x4 dacc[2];
    #pragma unroll
    for (int rb = 0; rb < 2; ++rb) {
        dacc[rb] = (f32x4){0.f, 0.f, 0.f, 0.f};
        #pragma unroll
        for (int eb = 0; eb < 4; ++eb) nacc[rb][eb] = (f32x4){0.f, 0.f, 0.f, 0.f};
    }
    bf16x8 ones;
    #pragma unroll
    for (int j = 0; j < 8; ++j) ones[j] = (short)0x3F80;

    const int lo_key = q0 - (W - 1);
    const int kt_lo = (lo_key <= 0) ? 0 : (lo_key >> 6);
    const int kt_hi = (q0 + 127) >> 6;

    for (int kt = kt_lo; kt <= kt_hi; ++kt) {
        const int k0 = kt << 6;
        __syncthreads();
        #pragma unroll
        for (int i = 0; i < 4; ++i) {
            int c = tid + THREADS * i;
            int row = c >> 4;
            int f0 = (c & 15) * 8;
            const float* src = (f0 < 64) ? (k  + base + (size_t)(k0 + row) * Dh + f0)
                                         : (kr + base + (size_t)(k0 + row) * Dh + (f0 - 64));
            f32x4 a = *(const f32x4*)src;
            f32x4 b = *(const f32x4*)(src + 4);
            bf16x8 w8;
            #pragma unroll
            for (int j = 0; j < 4; ++j) { w8[j] = f2bf(a[j]); w8[4 + j] = f2bf(b[j]); }
            int off = row * 256 + ((f0 * 2) ^ ((row & 7) << 4));
            *(bf16x8*)(sK + off) = w8;
        }
        #pragma unroll
        for (int i = 0; i < 4; ++i) {
            int c = tid + THREADS * i;
            int e = c & 63;
            int k4 = c >> 6;
            const float* src = v + base + (size_t)(k0 + k4 * 4) * Dh + e;
            bf16x4 w4;
            w4[0] = f2bf(src[0]); w4[1] = f2bf(src[Dh]);
            w4[2] = f2bf(src[2 * Dh]); w4[3] = f2bf(src[3 * Dh]);
            int off = e * 128 + ((k4 * 8) ^ ((e & 7) << 4));
            *(bf16x4*)(sV + off) = w4;
        }
        __syncthreads();

        const bool dense = (k0 + 63 <= q0) && (k0 >= q0 + 127 - (W - 1));
        #pragma unroll
        for (int kb = 0; kb < 4; ++kb) {
            bf16x8 kf[4];
            const int key = kb * 16 + l16;
            const int rowoff = key * 256;
            const int sw = (key & 7) << 4;
            #pragma unroll
            for (int fb = 0; fb < 4; ++fb)
                kf[fb] = *(const bf16x8*)(sK + rowoff + ((fb * 64 + g * 16) ^ sw));
            #pragma unroll
            for (int rb = 0; rb < 2; ++rb) {
                f32x4 s = {0.f, 0.f, 0.f, 0.f};
                #pragma unroll
                for (int fb = 0; fb < 4; ++fb)
                    s = __builtin_amdgcn_mfma_f32_16x16x32_bf16(qf[rb][fb], kf[fb], s, 0, 0, 0);
                const int qrow0 = rb * 16 + g * 4;
                const int qg0 = q0 + wv * 32 + qrow0;
                const int mg = k0 + kb * 16 + l16;
                if (!dense) {
                    #pragma unroll
                    for (int r = 0; r < 4; ++r) {
                        unsigned d = (unsigned)(qg0 + r - mg);
                        if (d >= (unsigned)W) s[r] = 0.f;
                    }
                }
                #pragma unroll
                for (int r = 0; r < 4; ++r) {
                    int row = qrow0 + r;
                    int off = row * 128 + (((kb * 16 + l16) * 2) ^ ((row & 7) << 4));
                    *(short*)(sS[wv] + off) = f2bf(s[r]);
                }
            }
        }
        #pragma unroll
        for (int kb2 = 0; kb2 < 2; ++kb2) {
            bf16x8 af[2];
            #pragma unroll
            for (int rb = 0; rb < 2; ++rb) {
                int row = rb * 16 + l16;
                int off = row * 128 + ((kb2 * 64 + g * 16) ^ ((row & 7) << 4));
                af[rb] = *(const bf16x8*)(sS[wv] + off);
            }
            #pragma unroll
            for (int rb = 0; rb < 2; ++rb)
                dacc[rb] = __builtin_amdgcn_mfma_f32_16x16x32_bf16(af[rb], ones, dacc[rb], 0, 0, 0);
            #pragma unroll
            for (int eb = 0; eb < 4; ++eb) {
                int e = eb * 16 + l16;
                int off = e * 128 + ((kb2 * 64 + g * 16) ^ ((e & 7) << 4));
                bf16x8 bfr = *(const bf16x8*)(sV + off);
                #pragma unroll
                for (int rb = 0; rb < 2; ++rb)
                    nacc[rb][eb] = __builtin_amdgcn_mfma_f32_16x16x32_bf16(af[rb], bfr, nacc[rb][eb], 0, 0, 0);
            }
        }
    }

    #pragma unroll
    for (int rb = 0; rb < 2; ++rb) {
        f32x4 rc;
        #pragma unroll
        for (int r = 0; r < 4; ++r) rc[r] = 1.0f / (dacc[rb][r] + 1e-12f);
        const int qg0 = q0 + wv * 32 + rb * 16 + g * 4;
        #pragma unroll
        for (int eb = 0; eb < 4; ++eb) {
            #pragma unroll
            for (int r = 0; r < 4; ++r) {
                out[base + (size_t)(qg0 + r) * Dh + eb * 16 + l16] = nacc[rb][eb][r] * rc[r];
            }
        }
    }
}

extern "C" void kernel_launch(void* const* d_in, const int* in_sizes, int n_in,
                              void* d_out, int out_size, void* d_ws, size_t ws_size,
                              hipStream_t stream) {
    const float* q  = (const float*)d_in[0];
    const float* k  = (const float*)d_in[1];
    const float* qr = (const float*)d_in[2];
    const float* kr = (const float*)d_in[3];
    const float* v  = (const float*)d_in[4];
    const int* hor  = (const int*)d_in[5];
    float* out = (float*)d_out;
    const int BH = in_sizes[0] / (S_LEN * Dh);   // 16

    if (ws_size >= WS_NEED) {
        hipLaunchKernelGGL(prepack, dim3(4096), dim3(THREADS), 0, stream,
                           k, kr, v, (char*)d_ws);
        hipLaunchKernelGGL(swin_attn2, dim3((S_LEN / 128) * BH), dim3(THREADS), 0, stream,
                           q, qr, (const char*)d_ws, hor, out);
    } else {
        hipLaunchKernelGGL(swin_attn_fb, dim3(S_LEN / 128, BH), dim3(THREADS), 0, stream,
                           q, k, qr, kr, v, hor, out);
    }
}

// Round 4
// 45.948 us; speedup vs baseline: 1.2659x; 1.1460x over previous
//
#include <hip/hip_runtime.h>

#define S_LEN 4096
#define Dh 64
#define THREADS 256
#define KC_TILE 16384
#define VT_TILE 8192
#define VT_BASE 16777216ull
#define WS_NEED 25165824ull

typedef __attribute__((ext_vector_type(8))) short bf16x8;
typedef __attribute__((ext_vector_type(4))) short bf16x4;
typedef __attribute__((ext_vector_type(4))) float f32x4;
typedef __attribute__((ext_vector_type(16))) float f32x16;
typedef __attribute__((ext_vector_type(4))) unsigned u32x4;

__device__ __forceinline__ short f2bf(float f) {
    union { float f; unsigned u; } c; c.f = f;
    unsigned u = c.u + 0x7FFFu + ((c.u >> 16) & 1u);
    return (short)(u >> 16);
}

__device__ __forceinline__ unsigned cvt_pk(float lo, float hi) {
    unsigned r;
    asm("v_cvt_pk_bf16_f32 %0, %1, %2" : "=v"(r) : "v"(lo), "v"(hi));
    return r;
}

__device__ __forceinline__ void pl32swap(unsigned& a, unsigned& b) {
    asm("v_permlane32_swap_b32 %0, %1" : "+v"(a), "+v"(b));
}

__device__ __forceinline__ void gload16(const void* g, void* l) {
    __builtin_amdgcn_global_load_lds(
        (const __attribute__((address_space(1))) unsigned int*)g,
        (__attribute__((address_space(3))) unsigned int*)l, 16, 0, 0);
}

// ---------------- prepack (unchanged, proven): fp32 -> bf16 swizzled tile images
// Kc image per (bh, tile): key row r (0..63), feat f (0..127 = k||kr):
//   byte = r*256 + ((f*2) ^ ((r&7)<<4)); 16KB/tile at base 0.
// Vt image per (bh, tile): e (0..63), key kk (0..63):
//   byte = e*128 + ((kk*2) ^ ((e&7)<<4)); 8KB/tile at base VT_BASE.
__global__ __launch_bounds__(THREADS) void prepack(
    const float* __restrict__ k, const float* __restrict__ kr,
    const float* __restrict__ v, char* __restrict__ ws)
{
    const int t = blockIdx.x * THREADS + threadIdx.x;
    {
        const int bh = t >> 16;
        const int r1 = t & 65535;
        const int tile = r1 >> 10;
        const int r2 = r1 & 1023;
        const int row = r2 >> 4;
        const int f0 = (r2 & 15) * 8;
        const size_t rbase = ((size_t)bh * S_LEN + tile * 64 + row) * Dh;
        const float* src = (f0 < 64) ? (k + rbase + f0) : (kr + rbase + (f0 - 64));
        f32x4 a = *(const f32x4*)src;
        f32x4 b = *(const f32x4*)(src + 4);
        bf16x8 w;
        #pragma unroll
        for (int j = 0; j < 4; ++j) { w[j] = f2bf(a[j]); w[4 + j] = f2bf(b[j]); }
        const int off = row * 256 + ((f0 * 2) ^ ((row & 7) << 4));
        *(bf16x8*)(ws + (size_t)(bh * 64 + tile) * KC_TILE + off) = w;
    }
    {
        const int bh = t >> 16;
        const int r1 = t & 65535;
        const int tile = r1 >> 10;
        const int r2 = r1 & 1023;
        const int e = r2 & 63;
        const int k4 = r2 >> 6;
        const float* src = v + ((size_t)bh * S_LEN + tile * 64 + k4 * 4) * Dh + e;
        bf16x4 w;
        w[0] = f2bf(src[0]);
        w[1] = f2bf(src[Dh]);
        w[2] = f2bf(src[2 * Dh]);
        w[3] = f2bf(src[3 * Dh]);
        const int off = e * 128 + ((k4 * 8) ^ ((e & 7) << 4));
        *(bf16x4*)(ws + VT_BASE + (size_t)(bh * 64 + tile) * VT_TILE + off) = w;
    }
}

// ---------------- main: swapped QK^T (32x32x16) + in-register P transpose
__global__ __launch_bounds__(THREADS, 2) void swin_attn3(
    const float* __restrict__ q, const float* __restrict__ qr,
    const char* __restrict__ ws, const int* __restrict__ hor,
    float* __restrict__ out)
{
    const int W = hor[0];
    const int bid = blockIdx.x;                     // 512 blocks, %8==0
    const int wg = (bid & 7) * 64 + (bid >> 3);     // XCD-aware bijective swizzle
    const int bh = wg >> 5;
    const int q0 = (wg & 31) * 128;
    const size_t base = (size_t)bh * S_LEN * Dh;

    const int tid = threadIdx.x;
    const int lane = tid & 63;
    const int wv = tid >> 6;        // wave owns q rows [q0+wv*32, +32)
    const int hi = lane >> 5;       // 0/1
    const int l32 = lane & 31;

    __shared__ __align__(16) char sK[2][KC_TILE];   // 32KB
    __shared__ __align__(16) char sV[2][VT_TILE];   // 16KB
    __shared__ float sD[4][32];

    const int qg = q0 + wv * 32 + l32;              // this lane's q-row

    // ---- Q fragments (B-operand: col=q=l32, k=hi*8+j), feat concat q||qr
    bf16x8 qf[8];
    {
        const float* qrow  = q  + base + (size_t)qg * Dh;
        const float* qrrow = qr + base + (size_t)qg * Dh;
        #pragma unroll
        for (int fs = 0; fs < 8; ++fs) {
            int feat = fs * 16 + hi * 8;
            const float* src = (feat < 64) ? (qrow + feat) : (qrrow + (feat - 64));
            f32x4 a = *(const f32x4*)src;
            f32x4 b = *(const f32x4*)(src + 4);
            bf16x8 fr;
            #pragma unroll
            for (int j = 0; j < 4; ++j) { fr[j] = f2bf(a[j]); fr[4 + j] = f2bf(b[j]); }
            qf[fs] = fr;
        }
    }

    f32x16 nacc0 = {};      // out[q][e], e in [0,32)
    f32x16 nacc1 = {};      // e in [32,64)
    float dsum = 0.f;

    const int lo_key = q0 - (W - 1);
    const int kt_lo = (lo_key <= 0) ? 0 : (lo_key >> 6);
    const int kt_hi = (q0 + 127) >> 6;

    const char* KcB = ws + (size_t)(bh << 6) * KC_TILE;
    const char* VtB = ws + VT_BASE + (size_t)(bh << 6) * VT_TILE;

    // Drain Q/hor loads so vmcnt counts ONLY staging loads.
    asm volatile("s_waitcnt vmcnt(0)" ::: "memory");
    __builtin_amdgcn_sched_barrier(0);

#define STAGE(B, KT)                                                              \
    do {                                                                          \
        const char* kg_ = KcB + (size_t)(KT) * KC_TILE + wv * 4096 + lane * 16;   \
        const char* vg_ = VtB + (size_t)(KT) * VT_TILE + wv * 2048 + lane * 16;   \
        _Pragma("unroll")                                                         \
        for (int i_ = 0; i_ < 4; ++i_)                                            \
            gload16(kg_ + i_ * 1024, &sK[B][wv * 4096 + i_ * 1024]);              \
        _Pragma("unroll")                                                         \
        for (int i_ = 0; i_ < 2; ++i_)                                            \
            gload16(vg_ + i_ * 1024, &sV[B][wv * 2048 + i_ * 1024]);              \
    } while (0)

    STAGE(0, kt_lo);

    int buf = 0;
    for (int kt = kt_lo; kt <= kt_hi; ++kt) {
        const int k0 = kt << 6;
        if (kt < kt_hi) {
            STAGE(buf ^ 1, kt + 1);                          // 12 outstanding
            asm volatile("s_waitcnt vmcnt(6)" ::: "memory"); // cur tile landed
        } else {
            asm volatile("s_waitcnt vmcnt(0)" ::: "memory");
        }
        __builtin_amdgcn_sched_barrier(0);
        __builtin_amdgcn_s_barrier();
        asm volatile("" ::: "memory");

        const char* Kb = sK[buf];
        const char* Vb = sV[buf];
        const bool dense = (k0 + 63 <= q0) && (k0 >= q0 + 128 - W);

        __builtin_amdgcn_s_setprio(1);

        // ---- swapped QK^T: S^T[key][q] = mfma(A=K, B=Q); two 32-key blocks
        f32x16 sac0 = {};
        f32x16 sac1 = {};
        const int krow0 = l32;
        const int krow1 = 32 + l32;
        const int sw0 = (krow0 & 7) << 4;      // == (krow1&7)<<4
        #pragma unroll
        for (int fs = 0; fs < 8; ++fs) {
            const int fb = (fs * 16 + hi * 8) * 2;
            bf16x8 kf0 = *(const bf16x8*)(Kb + krow0 * 256 + (fb ^ sw0));
            bf16x8 kf1 = *(const bf16x8*)(Kb + krow1 * 256 + (fb ^ sw0));
            sac0 = __builtin_amdgcn_mfma_f32_32x32x16_bf16(kf0, qf[fs], sac0, 0, 0, 0);
            sac1 = __builtin_amdgcn_mfma_f32_32x32x16_bf16(kf1, qf[fs], sac1, 0, 0, 0);
        }

        // ---- per 32-key block: mask, D-sum, cvt_pk+permlane transpose, PV
        #pragma unroll
        for (int kb = 0; kb < 2; ++kb) {
            f32x16 s = kb ? sac1 : sac0;
            if (!dense) {
                #pragma unroll
                for (int r = 0; r < 16; ++r) {
                    int key = k0 + kb * 32 + (r & 3) + 8 * (r >> 2) + 4 * hi;
                    if ((unsigned)(qg - key) >= (unsigned)W) s[r] = 0.f;
                }
            }
            #pragma unroll
            for (int r = 0; r < 16; ++r) dsum += s[r];

            unsigned w0 = cvt_pk(s[0],  s[1]);
            unsigned w1 = cvt_pk(s[2],  s[3]);
            unsigned w2 = cvt_pk(s[4],  s[5]);
            unsigned w3 = cvt_pk(s[6],  s[7]);
            unsigned w4 = cvt_pk(s[8],  s[9]);
            unsigned w5 = cvt_pk(s[10], s[11]);
            unsigned w6 = cvt_pk(s[12], s[13]);
            unsigned w7 = cvt_pk(s[14], s[15]);
            pl32swap(w0, w2);   // -> pa0.word0 / pa0.word2
            pl32swap(w1, w3);   // -> pa0.word1 / pa0.word3
            pl32swap(w4, w6);   // -> pa1.word0 / pa1.word2
            pl32swap(w5, w7);   // -> pa1.word1 / pa1.word3
            u32x4 p0v = {w0, w1, w2, w3};
            u32x4 p1v = {w4, w5, w6, w7};
            bf16x8 pa0 = __builtin_bit_cast(bf16x8, p0v);
            bf16x8 pa1 = __builtin_bit_cast(bf16x8, p1v);

            #pragma unroll
            for (int ks = 0; ks < 2; ++ks) {
                bf16x8 pa = ks ? pa1 : pa0;
                const int keyb = (kb * 32 + ks * 16 + hi * 8) * 2;
                const int e0 = l32;
                const int e1 = 32 + l32;
                const int swv = (l32 & 7) << 4;
                bf16x8 vf0 = *(const bf16x8*)(Vb + e0 * 128 + (keyb ^ swv));
                bf16x8 vf1 = *(const bf16x8*)(Vb + e1 * 128 + (keyb ^ swv));
                nacc0 = __builtin_amdgcn_mfma_f32_32x32x16_bf16(pa, vf0, nacc0, 0, 0, 0);
                nacc1 = __builtin_amdgcn_mfma_f32_32x32x16_bf16(pa, vf1, nacc1, 0, 0, 0);
            }
        }
        __builtin_amdgcn_s_setprio(0);

        asm volatile("" ::: "memory");
        __builtin_amdgcn_s_barrier();   // readers done before next STAGE overwrites
        buf ^= 1;
    }
#undef STAGE

    // ---- combine D halves (lane L holds keys of half hi only)
    unsigned da = __builtin_bit_cast(unsigned, dsum);
    unsigned db = da;
    pl32swap(da, db);
    float dfull = __builtin_bit_cast(float, da) + __builtin_bit_cast(float, db);
    float rcq = 1.0f / (dfull + 1e-12f);
    if (lane < 32) sD[wv][l32] = rcq;
    float rcv[16];
    #pragma unroll
    for (int r = 0; r < 16; ++r)
        rcv[r] = sD[wv][(r & 3) + 8 * (r >> 2) + 4 * hi];

    // ---- store out[q][e] = N * rc; C rows q = crow(r,hi), cols e = l32 (+32)
    #pragma unroll
    for (int r = 0; r < 16; ++r) {
        const int qrow = q0 + wv * 32 + (r & 3) + 8 * (r >> 2) + 4 * hi;
        float* o = out + base + (size_t)qrow * Dh + l32;
        o[0]  = nacc0[r] * rcv[r];
        o[32] = nacc1[r] * rcv[r];
    }
}

// ---------------- fallback (round-1 proven kernel) if ws too small
__global__ __launch_bounds__(THREADS, 2) void swin_attn_fb(
    const float* __restrict__ q, const float* __restrict__ k,
    const float* __restrict__ qr, const float* __restrict__ kr,
    const float* __restrict__ v, const int* __restrict__ hor,
    float* __restrict__ out)
{
    const int W = hor[0];
    const int q0 = blockIdx.x * 128;
    const int bh = blockIdx.y;
    const size_t base = (size_t)bh * S_LEN * Dh;

    const int tid = threadIdx.x;
    const int lane = tid & 63;
    const int wv = tid >> 6;
    const int g = lane >> 4;
    const int l16 = lane & 15;

    __shared__ __align__(16) char sK[64 * 256];
    __shared__ __align__(16) char sV[64 * 128];
    __shared__ __align__(16) char sS[4][32 * 128];

    typedef __attribute__((ext_vector_type(4))) float f4;
    bf16x8 qf[2][4];
    #pragma unroll
    for (int rb = 0; rb < 2; ++rb) {
        int qg = q0 + wv * 32 + rb * 16 + l16;
        const float* qrow  = q  + base + (size_t)qg * Dh;
        const float* qrrow = qr + base + (size_t)qg * Dh;
        #pragma unroll
        for (int fb = 0; fb < 4; ++fb) {
            int feat = fb * 32 + g * 8;
            const float* src = (feat < 64) ? (qrow + feat) : (qrrow + (feat - 64));
            f4 a = *(const f4*)src;
            f4 b = *(const f4*)(src + 4);
            bf16x8 fr;
            #pragma unroll
            for (int j = 0; j < 4; ++j) { fr[j] = f2bf(a[j]); fr[4 + j] = f2bf(b[j]); }
            qf[rb][fb] = fr;
        }
    }

    f32x4 nacc[2][4];
    f32x4 dacc[2];
    #pragma unroll
    for (int rb = 0; rb < 2; ++rb) {
        dacc[rb] = (f32x4){0.f, 0.f, 0.f, 0.f};
        #pragma unroll
        for (int eb = 0; eb < 4; ++eb) nacc[rb][eb] = (f32x4){0.f, 0.f, 0.f, 0.f};
    }
    bf16x8 ones;
    #pragma unroll
    for (int j = 0; j < 8; ++j) ones[j] = (short)0x3F80;

    const int lo_key = q0 - (W - 1);
    const int kt_lo = (lo_key <= 0) ? 0 : (lo_key >> 6);
    const int kt_hi = (q0 + 127) >> 6;

    for (int kt = kt_lo; kt <= kt_hi; ++kt) {
        const int k0 = kt << 6;
        __syncthreads();
        #pragma unroll
        for (int i = 0; i < 4; ++i) {
            int c = tid + THREADS * i;
            int row = c >> 4;
            int f0 = (c & 15) * 8;
            const float* src = (f0 < 64) ? (k  + base + (size_t)(k0 + row) * Dh + f0)
                                         : (kr + base + (size_t)(k0 + row) * Dh + (f0 - 64));
            f4 a = *(const f4*)src;
            f4 b = *(const f4*)(src + 4);
            bf16x8 w8;
            #pragma unroll
            for (int j = 0; j < 4; ++j) { w8[j] = f2bf(a[j]); w8[4 + j] = f2bf(b[j]); }
            int off = row * 256 + ((f0 * 2) ^ ((row & 7) << 4));
            *(bf16x8*)(sK + off) = w8;
        }
        #pragma unroll
        for (int i = 0; i < 4; ++i) {
            int c = tid + THREADS * i;
            int e = c & 63;
            int k4 = c >> 6;
            const float* src = v + base + (size_t)(k0 + k4 * 4) * Dh + e;
            bf16x4 w4;
            w4[0] = f2bf(src[0]); w4[1] = f2bf(src[Dh]);
            w4[2] = f2bf(src[2 * Dh]); w4[3] = f2bf(src[3 * Dh]);
            int off = e * 128 + ((k4 * 8) ^ ((e & 7) << 4));
            *(bf16x4*)(sV + off) = w4;
        }
        __syncthreads();

        const bool dense = (k0 + 63 <= q0) && (k0 >= q0 + 128 - W);
        #pragma unroll
        for (int kb = 0; kb < 4; ++kb) {
            bf16x8 kf[4];
            const int key = kb * 16 + l16;
            const int rowoff = key * 256;
            const int sw = (key & 7) << 4;
            #pragma unroll
            for (int fb = 0; fb < 4; ++fb)
                kf[fb] = *(const bf16x8*)(sK + rowoff + ((fb * 64 + g * 16) ^ sw));
            #pragma unroll
            for (int rb = 0; rb < 2; ++rb) {
                f32x4 s = {0.f, 0.f, 0.f, 0.f};
                #pragma unroll
                for (int fb = 0; fb < 4; ++fb)
                    s = __builtin_amdgcn_mfma_f32_16x16x32_bf16(qf[rb][fb], kf[fb], s, 0, 0, 0);
                const int qrow0 = rb * 16 + g * 4;
                const int qg0 = q0 + wv * 32 + qrow0;
                const int mg = k0 + kb * 16 + l16;
                if (!dense) {
                    #pragma unroll
                    for (int r = 0; r < 4; ++r) {
                        unsigned d = (unsigned)(qg0 + r - mg);
                        if (d >= (unsigned)W) s[r] = 0.f;
                    }
                }
                #pragma unroll
                for (int r = 0; r < 4; ++r) {
                    int row = qrow0 + r;
                    int off = row * 128 + (((kb * 16 + l16) * 2) ^ ((row & 7) << 4));
                    *(short*)(sS[wv] + off) = f2bf(s[r]);
                }
            }
        }
        #pragma unroll
        for (int kb2 = 0; kb2 < 2; ++kb2) {
            bf16x8 af[2];
            #pragma unroll
            for (int rb = 0; rb < 2; ++rb) {
                int row = rb * 16 + l16;
                int off = row * 128 + ((kb2 * 64 + g * 16) ^ ((row & 7) << 4));
                af[rb] = *(const bf16x8*)(sS[wv] + off);
            }
            #pragma unroll
            for (int rb = 0; rb < 2; ++rb)
                dacc[rb] = __builtin_amdgcn_mfma_f32_16x16x32_bf16(af[rb], ones, dacc[rb], 0, 0, 0);
            #pragma unroll
            for (int eb = 0; eb < 4; ++eb) {
                int e = eb * 16 + l16;
                int off = e * 128 + ((kb2 * 64 + g * 16) ^ ((e & 7) << 4));
                bf16x8 bfr = *(const bf16x8*)(sV + off);
                #pragma unroll
                for (int rb = 0; rb < 2; ++rb)
                    nacc[rb][eb] = __builtin_amdgcn_mfma_f32_16x16x32_bf16(af[rb], bfr, nacc[rb][eb], 0, 0, 0);
            }
        }
    }

    #pragma unroll
    for (int rb = 0; rb < 2; ++rb) {
        f32x4 rc;
        #pragma unroll
        for (int r = 0; r < 4; ++r) rc[r] = 1.0f / (dacc[rb][r] + 1e-12f);
        const int qg0 = q0 + wv * 32 + rb * 16 + g * 4;
        #pragma unroll
        for (int eb = 0; eb < 4; ++eb) {
            #pragma unroll
            for (int r = 0; r < 4; ++r) {
                out[base + (size_t)(qg0 + r) * Dh + eb * 16 + l16] = nacc[rb][eb][r] * rc[r];
            }
        }
    }
}

extern "C" void kernel_launch(void* const* d_in, const int* in_sizes, int n_in,
                              void* d_out, int out_size, void* d_ws, size_t ws_size,
                              hipStream_t stream) {
    const float* q  = (const float*)d_in[0];
    const float* k  = (const float*)d_in[1];
    const float* qr = (const float*)d_in[2];
    const float* kr = (const float*)d_in[3];
    const float* v  = (const float*)d_in[4];
    const int* hor  = (const int*)d_in[5];
    float* out = (float*)d_out;
    const int BH = in_sizes[0] / (S_LEN * Dh);   // 16

    if (ws_size >= WS_NEED) {
        hipLaunchKernelGGL(prepack, dim3(4096), dim3(THREADS), 0, stream,
                           k, kr, v, (char*)d_ws);
        hipLaunchKernelGGL(swin_attn3, dim3((S_LEN / 128) * BH), dim3(THREADS), 0, stream,
                           q, qr, (const char*)d_ws, hor, out);
    } else {
        hipLaunchKernelGGL(swin_attn_fb, dim3(S_LEN / 128, BH), dim3(THREADS), 0, stream,
                           q, k, qr, kr, v, hor, out);
    }
}

// Round 5
// 42.305 us; speedup vs baseline: 1.3748x; 1.0861x over previous
//
#include <hip/hip_runtime.h>

#define S_LEN 4096
#define Dh 64
#define KC_TILE 16384
#define VT_TILE 8192

typedef __attribute__((ext_vector_type(8))) short bf16x8;
typedef __attribute__((ext_vector_type(4))) short bf16x4;
typedef __attribute__((ext_vector_type(4))) float f32x4;
typedef __attribute__((ext_vector_type(16))) float f32x16;
typedef __attribute__((ext_vector_type(4))) unsigned u32x4;

__device__ __forceinline__ short f2bf(float f) {
    union { float f; unsigned u; } c; c.f = f;
    unsigned u = c.u + 0x7FFFu + ((c.u >> 16) & 1u);
    return (short)(u >> 16);
}

__device__ __forceinline__ unsigned cvt_pk(float lo, float hi) {
    unsigned r;
    asm("v_cvt_pk_bf16_f32 %0, %1, %2" : "=v"(r) : "v"(lo), "v"(hi));
    return r;
}

__device__ __forceinline__ void pl32swap(unsigned& a, unsigned& b) {
    asm("v_permlane32_swap_b32 %0, %1" : "+v"(a), "+v"(b));
}

// ---------------- prepack2: fp32 -> bf16 tiles in MFMA FRAGMENT ORDER.
// K region (base 0), per (bh,tile): 16 chunks of 1KB; chunk c = fs*2+half;
//   lane l bytes [c*1024+l*16, +16) = K[key=half*32+(l&31)][feat fs*16+(l>>5)*8 + j], j=0..7 (k||kr concat).
// V region (base vt_base), per (bh,tile): 8 chunks of 1KB; chunk c = kb*4+ks*2+eh;
//   lane l = V^T[e=eh*32+(l&31)][key kb*32+ks*16+(l>>5)*8 + j].
__global__ __launch_bounds__(256) void prepack2(
    const float* __restrict__ k, const float* __restrict__ kr,
    const float* __restrict__ v, char* __restrict__ ws,
    unsigned long long vt_base, int k_slots)
{
    const int t = blockIdx.x * 256 + threadIdx.x;
    if (t < k_slots) {
        const int bh = t >> 16;            // 64 tiles * 1024 slots per bh
        const int r = t & 65535;
        const int tile = r >> 10;
        const int s = r & 1023;
        const int l = s & 63;
        const int c = s >> 6;
        const int fs = c >> 1, half = c & 1;
        const int key = half * 32 + (l & 31);
        const int f0 = fs * 16 + (l >> 5) * 8;
        const size_t row = ((size_t)bh * S_LEN + tile * 64 + key) * Dh;
        const float* src = (f0 < 64) ? (k + row + f0) : (kr + row + f0 - 64);
        f32x4 a = *(const f32x4*)src;
        f32x4 b = *(const f32x4*)(src + 4);
        u32x4 w;
        w[0] = cvt_pk(a[0], a[1]); w[1] = cvt_pk(a[2], a[3]);
        w[2] = cvt_pk(b[0], b[1]); w[3] = cvt_pk(b[2], b[3]);
        *(u32x4*)(ws + (size_t)(bh * 64 + tile) * KC_TILE + s * 16) = w;
    } else {
        const int t2 = t - k_slots;        // 64 tiles * 512 slots per bh
        const int bh = t2 >> 15;
        const int r = t2 & 32767;
        const int tile = r >> 9;
        const int s = r & 511;
        const int l = s & 63;
        const int c = s >> 6;              // kb*4 + ks*2 + eh
        const int kb = c >> 2, ks = (c >> 1) & 1, eh = c & 1;
        const int e = eh * 32 + (l & 31);
        const int key0 = kb * 32 + ks * 16 + (l >> 5) * 8;
        const float* src = v + ((size_t)bh * S_LEN + tile * 64 + key0) * Dh + e;
        float x0 = src[0],      x1 = src[Dh],     x2 = src[2 * Dh], x3 = src[3 * Dh];
        float x4 = src[4 * Dh], x5 = src[5 * Dh], x6 = src[6 * Dh], x7 = src[7 * Dh];
        u32x4 w;
        w[0] = cvt_pk(x0, x1); w[1] = cvt_pk(x2, x3);
        w[2] = cvt_pk(x4, x5); w[3] = cvt_pk(x6, x7);
        *(u32x4*)(ws + vt_base + (size_t)(bh * 64 + tile) * VT_TILE + s * 16) = w;
    }
}

// ---------------- main: LDS-free, barrier-free, 1 wave/block, reg-resident fragments
__global__ __launch_bounds__(64, 2) void swin_attn4(
    const float* __restrict__ q, const float* __restrict__ qr,
    const char* __restrict__ ws, unsigned long long vt_base,
    const int* __restrict__ hor, float* __restrict__ out)
{
    const int W = hor[0];
    const int nwg = gridDim.x;                     // BH*128, %8==0
    const int cpx = nwg >> 3;
    const int bid = blockIdx.x;
    const int wg = (bid & 7) * cpx + (bid >> 3);   // XCD-aware bijective swizzle
    const int bh = wg >> 7;
    const int q0 = (wg & 127) * 32;
    const size_t base = (size_t)bh * S_LEN * Dh;

    const int lane = threadIdx.x;
    const int hi = lane >> 5;
    const int l32 = lane & 31;

    __shared__ float sD[32];

    const int qg = q0 + l32;                       // this lane's q-row

    // ---- Q fragments (B-operand: col=q=l32, k=hi*8+j), feat concat q||qr
    bf16x8 qf[8];
    {
        const float* qrow  = q  + base + (size_t)qg * Dh;
        const float* qrrow = qr + base + (size_t)qg * Dh;
        #pragma unroll
        for (int fs = 0; fs < 8; ++fs) {
            int feat = fs * 16 + hi * 8;
            const float* src = (feat < 64) ? (qrow + feat) : (qrrow + feat - 64);
            f32x4 a = *(const f32x4*)src;
            f32x4 b = *(const f32x4*)(src + 4);
            u32x4 w;
            w[0] = cvt_pk(a[0], a[1]); w[1] = cvt_pk(a[2], a[3]);
            w[2] = cvt_pk(b[0], b[1]); w[3] = cvt_pk(b[2], b[3]);
            qf[fs] = __builtin_bit_cast(bf16x8, w);
        }
    }

    f32x16 nacc0 = {};          // out[q][e], e in [0,32)
    f32x16 nacc1 = {};          // e in [32,64)
    float dsum = 0.f;

    const int lo_key = q0 - (W - 1);
    const int kt_lo = (lo_key <= 0) ? 0 : (lo_key >> 6);
    const int kt_hi = (q0 + 31) >> 6;

    const char* Kc = ws + (size_t)(bh << 6) * KC_TILE + lane * 16;
    const char* Vt = ws + vt_base + (size_t)(bh << 6) * VT_TILE + lane * 16;

    bf16x8 kf[16];
    bf16x8 vf[8];
    {   // prologue: tile kt_lo into registers
        const char* kp = Kc + (size_t)kt_lo * KC_TILE;
        const char* vp = Vt + (size_t)kt_lo * VT_TILE;
        #pragma unroll
        for (int c = 0; c < 16; ++c) kf[c] = *(const bf16x8*)(kp + c * 1024);
        #pragma unroll
        for (int c = 0; c < 8; ++c)  vf[c] = *(const bf16x8*)(vp + c * 1024);
    }

    for (int kt = kt_lo; kt <= kt_hi; ++kt) {
        const int k0 = kt << 6;
        const int ktn = (kt < kt_hi) ? kt + 1 : kt_hi;   // clamp (last reload harmless)
        const bool dense = (k0 + 63 <= q0) && (k0 >= q0 + 32 - W);

        // ---- swapped QK^T: S^T[key][q] = mfma(A=K, B=Q), two 32-key halves
        f32x16 sac0 = {};
        f32x16 sac1 = {};
        __builtin_amdgcn_s_setprio(1);
        #pragma unroll
        for (int fs = 0; fs < 8; ++fs) {
            sac0 = __builtin_amdgcn_mfma_f32_32x32x16_bf16(kf[fs * 2],     qf[fs], sac0, 0, 0, 0);
            sac1 = __builtin_amdgcn_mfma_f32_32x32x16_bf16(kf[fs * 2 + 1], qf[fs], sac1, 0, 0, 0);
        }
        __builtin_amdgcn_s_setprio(0);

        // ---- prefetch next K tile (kf regs dead after QK; WAR sets issue point)
        {
            const char* kp = Kc + (size_t)ktn * KC_TILE;
            #pragma unroll
            for (int c = 0; c < 16; ++c) kf[c] = *(const bf16x8*)(kp + c * 1024);
        }

        // ---- per 32-key half: mask, D-sum, cvt_pk+permlane transpose, PV
        #pragma unroll
        for (int kb = 0; kb < 2; ++kb) {
            f32x16 s = kb ? sac1 : sac0;
            if (!dense) {
                #pragma unroll
                for (int r = 0; r < 16; ++r) {
                    int key = k0 + kb * 32 + (r & 3) + 8 * (r >> 2) + 4 * hi;
                    if ((unsigned)(qg - key) >= (unsigned)W) s[r] = 0.f;
                }
            }
            #pragma unroll
            for (int r = 0; r < 16; ++r) dsum += s[r];

            unsigned w0 = cvt_pk(s[0],  s[1]);
            unsigned w1 = cvt_pk(s[2],  s[3]);
            unsigned w2 = cvt_pk(s[4],  s[5]);
            unsigned w3 = cvt_pk(s[6],  s[7]);
            unsigned w4 = cvt_pk(s[8],  s[9]);
            unsigned w5 = cvt_pk(s[10], s[11]);
            unsigned w6 = cvt_pk(s[12], s[13]);
            unsigned w7 = cvt_pk(s[14], s[15]);
            pl32swap(w0, w2);
            pl32swap(w1, w3);
            pl32swap(w4, w6);
            pl32swap(w5, w7);
            u32x4 p0v = {w0, w1, w2, w3};
            u32x4 p1v = {w4, w5, w6, w7};
            bf16x8 pa0 = __builtin_bit_cast(bf16x8, p0v);
            bf16x8 pa1 = __builtin_bit_cast(bf16x8, p1v);

            __builtin_amdgcn_s_setprio(1);
            #pragma unroll
            for (int ks = 0; ks < 2; ++ks) {
                bf16x8 pa = ks ? pa1 : pa0;
                nacc0 = __builtin_amdgcn_mfma_f32_32x32x16_bf16(pa, vf[kb * 4 + ks * 2],     nacc0, 0, 0, 0);
                nacc1 = __builtin_amdgcn_mfma_f32_32x32x16_bf16(pa, vf[kb * 4 + ks * 2 + 1], nacc1, 0, 0, 0);
            }
            __builtin_amdgcn_s_setprio(0);
        }

        // ---- prefetch next V tile (vf dead after PV)
        {
            const char* vp = Vt + (size_t)ktn * VT_TILE;
            #pragma unroll
            for (int c = 0; c < 8; ++c) vf[c] = *(const bf16x8*)(vp + c * 1024);
        }
    }

    // ---- combine D halves; broadcast rc per q-row via tiny per-wave LDS
    unsigned da = __builtin_bit_cast(unsigned, dsum);
    unsigned db = da;
    pl32swap(da, db);
    float dfull = __builtin_bit_cast(float, da) + __builtin_bit_cast(float, db);
    float rcq = 1.0f / (dfull + 1e-12f);
    if (lane < 32) sD[l32] = rcq;
    __syncthreads();
    float rcv[16];
    #pragma unroll
    for (int r = 0; r < 16; ++r)
        rcv[r] = sD[(r & 3) + 8 * (r >> 2) + 4 * hi];

    #pragma unroll
    for (int r = 0; r < 16; ++r) {
        const int qrow = q0 + (r & 3) + 8 * (r >> 2) + 4 * hi;
        float* o = out + base + (size_t)qrow * Dh + l32;
        o[0]  = nacc0[r] * rcv[r];
        o[32] = nacc1[r] * rcv[r];
    }
}

// ---------------- fallback (round-1 proven kernel) if ws too small
__global__ __launch_bounds__(256, 2) void swin_attn_fb(
    const float* __restrict__ q, const float* __restrict__ k,
    const float* __restrict__ qr, const float* __restrict__ kr,
    const float* __restrict__ v, const int* __restrict__ hor,
    float* __restrict__ out)
{
    const int W = hor[0];
    const int q0 = blockIdx.x * 128;
    const int bh = blockIdx.y;
    const size_t base = (size_t)bh * S_LEN * Dh;

    const int tid = threadIdx.x;
    const int lane = tid & 63;
    const int wv = tid >> 6;
    const int g = lane >> 4;
    const int l16 = lane & 15;

    __shared__ __align__(16) char sK[64 * 256];
    __shared__ __align__(16) char sV[64 * 128];
    __shared__ __align__(16) char sS[4][32 * 128];

    bf16x8 qf[2][4];
    #pragma unroll
    for (int rb = 0; rb < 2; ++rb) {
        int qg = q0 + wv * 32 + rb * 16 + l16;
        const float* qrow  = q  + base + (size_t)qg * Dh;
        const float* qrrow = qr + base + (size_t)qg * Dh;
        #pragma unroll
        for (int fb = 0; fb < 4; ++fb) {
            int feat = fb * 32 + g * 8;
            const float* src = (feat < 64) ? (qrow + feat) : (qrrow + (feat - 64));
            f32x4 a = *(const f32x4*)src;
            f32x4 b = *(const f32x4*)(src + 4);
            bf16x8 fr;
            #pragma unroll
            for (int j = 0; j < 4; ++j) { fr[j] = f2bf(a[j]); fr[4 + j] = f2bf(b[j]); }
            qf[rb][fb] = fr;
        }
    }

    f32x4 nacc[2][4];
    f32x4 dacc[2];
    #pragma unroll
    for (int rb = 0; rb < 2; ++rb) {
        dacc[rb] = (f32x4){0.f, 0.f, 0.f, 0.f};
        #pragma unroll
        for (int eb = 0; eb < 4; ++eb) nacc[rb][eb] = (f32x4){0.f, 0.f, 0.f, 0.f};
    }
    bf16x8 ones;
    #pragma unroll
    for (int j = 0; j < 8; ++j) ones[j] = (short)0x3F80;

    const int lo_key = q0 - (W - 1);
    const int kt_lo = (lo_key <= 0) ? 0 : (lo_key >> 6);
    const int kt_hi = (q0 + 127) >> 6;

    for (int kt = kt_lo; kt <= kt_hi; ++kt) {
        const int k0 = kt << 6;
        __syncthreads();
        #pragma unroll
        for (int i = 0; i < 4; ++i) {
            int c = tid + 256 * i;
            int row = c >> 4;
            int f0 = (c & 15) * 8;
            const float* src = (f0 < 64) ? (k  + base + (size_t)(k0 + row) * Dh + f0)
                                         : (kr + base + (size_t)(k0 + row) * Dh + (f0 - 64));
            f32x4 a = *(const f32x4*)src;
            f32x4 b = *(const f32x4*)(src + 4);
            bf16x8 w8;
            #pragma unroll
            for (int j = 0; j < 4; ++j) { w8[j] = f2bf(a[j]); w8[4 + j] = f2bf(b[j]); }
            int off = row * 256 + ((f0 * 2) ^ ((row & 7) << 4));
            *(bf16x8*)(sK + off) = w8;
        }
        #pragma unroll
        for (int i = 0; i < 4; ++i) {
            int c = tid + 256 * i;
            int e = c & 63;
            int k4 = c >> 6;
            const float* src = v + base + (size_t)(k0 + k4 * 4) * Dh + e;
            bf16x4 w4;
            w4[0] = f2bf(src[0]); w4[1] = f2bf(src[Dh]);
            w4[2] = f2bf(src[2 * Dh]); w4[3] = f2bf(src[3 * Dh]);
            int off = e * 128 + ((k4 * 8) ^ ((e & 7) << 4));
            *(bf16x4*)(sV + off) = w4;
        }
        __syncthreads();

        const bool dense = (k0 + 63 <= q0) && (k0 >= q0 + 128 - W);
        #pragma unroll
        for (int kb = 0; kb < 4; ++kb) {
            bf16x8 kf[4];
            const int key = kb * 16 + l16;
            const int rowoff = key * 256;
            const int sw = (key & 7) << 4;
            #pragma unroll
            for (int fb = 0; fb < 4; ++fb)
                kf[fb] = *(const bf16x8*)(sK + rowoff + ((fb * 64 + g * 16) ^ sw));
            #pragma unroll
            for (int rb = 0; rb < 2; ++rb) {
                f32x4 s = {0.f, 0.f, 0.f, 0.f};
                #pragma unroll
                for (int fb = 0; fb < 4; ++fb)
                    s = __builtin_amdgcn_mfma_f32_16x16x32_bf16(qf[rb][fb], kf[fb], s, 0, 0, 0);
                const int qrow0 = rb * 16 + g * 4;
                const int qg0 = q0 + wv * 32 + qrow0;
                const int mg = k0 + kb * 16 + l16;
                if (!dense) {
                    #pragma unroll
                    for (int r = 0; r < 4; ++r) {
                        unsigned d = (unsigned)(qg0 + r - mg);
                        if (d >= (unsigned)W) s[r] = 0.f;
                    }
                }
                #pragma unroll
                for (int r = 0; r < 4; ++r) {
                    int row = qrow0 + r;
                    int off = row * 128 + (((kb * 16 + l16) * 2) ^ ((row & 7) << 4));
                    *(short*)(sS[wv] + off) = f2bf(s[r]);
                }
            }
        }
        #pragma unroll
        for (int kb2 = 0; kb2 < 2; ++kb2) {
            bf16x8 af[2];
            #pragma unroll
            for (int rb = 0; rb < 2; ++rb) {
                int row = rb * 16 + l16;
                int off = row * 128 + ((kb2 * 64 + g * 16) ^ ((row & 7) << 4));
                af[rb] = *(const bf16x8*)(sS[wv] + off);
            }
            #pragma unroll
            for (int rb = 0; rb < 2; ++rb)
                dacc[rb] = __builtin_amdgcn_mfma_f32_16x16x32_bf16(af[rb], ones, dacc[rb], 0, 0, 0);
            #pragma unroll
            for (int eb = 0; eb < 4; ++eb) {
                int e = eb * 16 + l16;
                int off = e * 128 + ((kb2 * 64 + g * 16) ^ ((e & 7) << 4));
                bf16x8 bfr = *(const bf16x8*)(sV + off);
                #pragma unroll
                for (int rb = 0; rb < 2; ++rb)
                    nacc[rb][eb] = __builtin_amdgcn_mfma_f32_16x16x32_bf16(af[rb], bfr, nacc[rb][eb], 0, 0, 0);
            }
        }
    }

    #pragma unroll
    for (int rb = 0; rb < 2; ++rb) {
        f32x4 rc;
        #pragma unroll
        for (int r = 0; r < 4; ++r) rc[r] = 1.0f / (dacc[rb][r] + 1e-12f);
        const int qg0 = q0 + wv * 32 + rb * 16 + g * 4;
        #pragma unroll
        for (int eb = 0; eb < 4; ++eb) {
            #pragma unroll
            for (int r = 0; r < 4; ++r) {
                out[base + (size_t)(qg0 + r) * Dh + eb * 16 + l16] = nacc[rb][eb][r] * rc[r];
            }
        }
    }
}

extern "C" void kernel_launch(void* const* d_in, const int* in_sizes, int n_in,
                              void* d_out, int out_size, void* d_ws, size_t ws_size,
                              hipStream_t stream) {
    const float* q  = (const float*)d_in[0];
    const float* k  = (const float*)d_in[1];
    const float* qr = (const float*)d_in[2];
    const float* kr = (const float*)d_in[3];
    const float* v  = (const float*)d_in[4];
    const int* hor  = (const int*)d_in[5];
    float* out = (float*)d_out;

    const int BH = in_sizes[0] / (S_LEN * Dh);                       // 16
    const unsigned long long vt_base = (unsigned long long)BH * 64 * KC_TILE;
    const unsigned long long ws_need = (unsigned long long)BH * 64 * (KC_TILE + VT_TILE);
    const int k_slots = BH * 65536;

    if (ws_size >= ws_need) {
        const int total_slots = BH * (65536 + 32768);
        hipLaunchKernelGGL(prepack2, dim3(total_slots / 256), dim3(256), 0, stream,
                           k, kr, v, (char*)d_ws, vt_base, k_slots);
        hipLaunchKernelGGL(swin_attn4, dim3(BH * 128), dim3(64), 0, stream,
                           q, qr, (const char*)d_ws, vt_base, hor, out);
    } else {
        hipLaunchKernelGGL(swin_attn_fb, dim3(S_LEN / 128, BH), dim3(256), 0, stream,
                           q, k, qr, kr, v, hor, out);
    }
}